// Round 5
// baseline (13609.732 us; speedup 1.0000x reference)
//
#include <hip/hip_runtime.h>
#include <math.h>

#define B_  256
#define T_  512
#define D_  256
#define H_  1024
#define O_  128
#define N4H 4096          // 4*H

typedef __attribute__((ext_vector_type(8))) short bf16x8;
typedef __attribute__((ext_vector_type(4))) float f32x4;

__device__ __forceinline__ unsigned short f2bf(float x) {
    union { float f; unsigned u; } v; v.f = x;
    unsigned r = v.u + 0x7fffu + ((v.u >> 16) & 1u);
    return (unsigned short)(r >> 16);
}
__device__ __forceinline__ float bf2f(unsigned short b) {
    union { float f; unsigned u; } v; v.u = ((unsigned)b) << 16;
    return v.f;
}
// cheap split: hi = truncated top-16, lo = rne(w - hi).
__device__ __forceinline__ void splitf(float w, short& hi, short& lo) {
    union { float f; unsigned u; } v; v.f = w;
    union { float f; unsigned u; } hf; hf.u = v.u & 0xffff0000u;
    hi = (short)(unsigned short)(v.u >> 16);
    lo = (short)f2bf(w - hf.f);
}

// 4 coherent 16B loads (sc0 sc1: bypass L1/L2, served at L3), single wait
// inside the asm (rule-18 safe: consumers depend on output regs).
__device__ __forceinline__ void load_h4(
    const unsigned short* a0, const unsigned short* a1,
    const unsigned short* b0, const unsigned short* b1,
    bf16x8& r0, bf16x8& r1, bf16x8& r2, bf16x8& r3)
{
    asm volatile(
        "global_load_dwordx4 %0, %4, off sc0 sc1\n\t"
        "global_load_dwordx4 %1, %5, off sc0 sc1\n\t"
        "global_load_dwordx4 %2, %6, off sc0 sc1\n\t"
        "global_load_dwordx4 %3, %7, off sc0 sc1\n\t"
        "s_waitcnt vmcnt(0)"
        : "=&v"(r0), "=&v"(r1), "=&v"(r2), "=&v"(r3)
        : "v"(a0), "v"(a1), "v"(b0), "v"(b1)
        : "memory");
}

// Coherent 4B store (write to coherence point, no dirty L2 lines).
__device__ __forceinline__ void store_h4(unsigned short* p, unsigned int d) {
    asm volatile("global_store_dword %0, %1, off sc0 sc1"
                 :: "v"(p), "v"(d) : "memory");
}

// Explicit drain of ALL vmem (covers inline-asm stores the compiler's
// waitcnt tracking does not see). Must run in every thread before the
// __syncthreads() that precedes the cluster-barrier signal.
__device__ __forceinline__ void drain_vmem() {
    asm volatile("s_waitcnt vmcnt(0)" ::: "memory");
}

// ---------------------------------------------------------------------------
// Pack weights, gate-interleaved rows n' = 4*j + gate (0=g,1=i,2=f,3=o).
// ---------------------------------------------------------------------------
__global__ __launch_bounds__(256) void pack_weights(
    const float* __restrict__ Wgx, const float* __restrict__ bgx, const float* __restrict__ Wgh,
    const float* __restrict__ Wix, const float* __restrict__ bix, const float* __restrict__ Wih,
    const float* __restrict__ Wfx, const float* __restrict__ bfx, const float* __restrict__ Wfh,
    const float* __restrict__ Wox, const float* __restrict__ box, const float* __restrict__ Woh,
    unsigned short* __restrict__ Whhi, unsigned short* __restrict__ Whlo,
    unsigned short* __restrict__ WXhi, unsigned short* __restrict__ WXlo,
    float* __restrict__ biasP)
{
    int idx = blockIdx.x * 256 + threadIdx.x;
    const int K = H_ + D_;
    const int total = N4H * K;
    if (idx < total) {
        int np = idx / K;
        int k  = idx - np * K;
        int j = np >> 2, g = np & 3;
        const float* Wh = (g == 0) ? Wgh : (g == 1) ? Wih : (g == 2) ? Wfh : Woh;
        const float* Wx = (g == 0) ? Wgx : (g == 1) ? Wix : (g == 2) ? Wfx : Wox;
        float w = (k < H_) ? Wh[j * H_ + k] : Wx[j * D_ + (k - H_)];
        unsigned short hi = f2bf(w);
        unsigned short lo = f2bf(w - bf2f(hi));
        if (k < H_) { Whhi[np * H_ + k] = hi; Whlo[np * H_ + k] = lo; }
        else        { WXhi[np * D_ + (k - H_)] = hi; WXlo[np * D_ + (k - H_)] = lo; }
    }
    if (idx < N4H) {
        int j = idx >> 2, g = idx & 3;
        const float* bx = (g == 0) ? bgx : (g == 1) ? bix : (g == 2) ? bfx : box;
        biasP[idx] = bx[j];
    }
}

// ---------------------------------------------------------------------------
// Incremental xz producer. One "unit" = 32 rows x 64 cols x K=32 of the
// 3-pass x-projection GEMM. A tile (one t, 32x128) = 16 units; after the
// 8 units of a 64-col half complete, the half is written out (+bias).
// ---------------------------------------------------------------------------
struct Prod {
    int t;                 // tile t_rel within next chunk (stride 8 by wave)
    int u;                 // unit index within tile, 0..15
    f32x4 xa[2][4];        // accumulator for current 64-col half
};

__device__ __forceinline__ void prod_zero(Prod& P) {
    #pragma unroll
    for (int rs = 0; rs < 2; ++rs)
        #pragma unroll
        for (int cs = 0; cs < 4; ++cs)
            P.xa[rs][cs] = (f32x4){0.f, 0.f, 0.f, 0.f};
}

__device__ __forceinline__ void prod_unit(
    Prod& P, int tcn, int nt0,
    const float* __restrict__ x,
    const unsigned short* __restrict__ WXhi,
    const unsigned short* __restrict__ WXlo,
    const float* __restrict__ biasP,
    float* __restrict__ xzn,
    int rbase, int cbase, int lrow, int quad)
{
    if (P.t >= tcn) return;
    const int kc   = (P.u & 7) * 32;
    const int half = P.u >> 3;
    const int t    = nt0 + P.t;

    bf16x8 Ahi[2], Alo[2];
    #pragma unroll
    for (int rs = 0; rs < 2; ++rs) {
        int b = rbase + rs * 16 + lrow;
        const float* p = x + (size_t)b * (T_ * D_) + (size_t)t * D_ + kc + quad * 8;
        float4 v0 = *(const float4*)p;
        float4 v1 = *(const float4*)(p + 4);
        float vv[8] = {v0.x, v0.y, v0.z, v0.w, v1.x, v1.y, v1.z, v1.w};
        #pragma unroll
        for (int j = 0; j < 8; ++j) {
            short hi, lo; splitf(vv[j], hi, lo);
            Ahi[rs][j] = hi; Alo[rs][j] = lo;
        }
    }
    bf16x8 Bh[4], Bl[4];
    #pragma unroll
    for (int cs = 0; cs < 4; ++cs) {
        int off = (cbase + half * 64 + cs * 16 + lrow) * D_ + kc + quad * 8;
        Bh[cs] = *(const bf16x8*)(WXhi + off);
        Bl[cs] = *(const bf16x8*)(WXlo + off);
    }
    #pragma unroll
    for (int rs = 0; rs < 2; ++rs)
        #pragma unroll
        for (int cs = 0; cs < 4; ++cs) {
            P.xa[rs][cs] = __builtin_amdgcn_mfma_f32_16x16x32_bf16(Ahi[rs], Bh[cs], P.xa[rs][cs], 0, 0, 0);
            P.xa[rs][cs] = __builtin_amdgcn_mfma_f32_16x16x32_bf16(Ahi[rs], Bl[cs], P.xa[rs][cs], 0, 0, 0);
            P.xa[rs][cs] = __builtin_amdgcn_mfma_f32_16x16x32_bf16(Alo[rs], Bh[cs], P.xa[rs][cs], 0, 0, 0);
        }

    P.u += 1;
    if ((P.u & 7) == 0) {
        // finished K=256 for this 64-col half: write out (+bias)
        #pragma unroll
        for (int cs = 0; cs < 4; ++cs) {
            int col = cbase + half * 64 + cs * 16 + lrow;
            float bv = biasP[col];
            #pragma unroll
            for (int rs = 0; rs < 2; ++rs) {
                int row0 = rbase + rs * 16 + quad * 4;
                #pragma unroll
                for (int r = 0; r < 4; ++r)
                    xzn[(size_t)(P.t * B_ + row0 + r) * N4H + col] = P.xa[rs][cs][r] + bv;
            }
        }
        prod_zero(P);
        if (P.u == 16) { P.u = 0; P.t += 8; }
    }
}

// ---------------------------------------------------------------------------
// Persistent kernel: all 512 LSTM steps in one cooperative launch.
// 256 blocks x 512 threads (8 waves), 1 block/CU (LDS-limited).
// Partition: 8 clusters (rg) x 32 blocks (cgi). Block tile: 32 rows x 128
// packed cols. Waves split K (1024 -> 8 x 128); LDS reduce of 8 partials.
// h exchange: sc0/sc1 L3-coherent loads/stores, NO fences -> weights stay
// L2-resident all run. Barrier: per-rg 32-block monotone counter; the
// barrier bubble is filled with xz production for the NEXT chunk.
// c state lives in 2 VGPRs per thread.
// ---------------------------------------------------------------------------
__global__ __launch_bounds__(512, 2) void lstm_persistent(
    const float* __restrict__ x,
    const unsigned short* __restrict__ Whhi, const unsigned short* __restrict__ Whlo,
    const unsigned short* __restrict__ WXhi, const unsigned short* __restrict__ WXlo,
    const float* __restrict__ biasP,
    unsigned short* __restrict__ h0hi, unsigned short* __restrict__ h0lo,
    unsigned short* __restrict__ h1hi, unsigned short* __restrict__ h1lo,
    float* xzA, float* xzB,
    unsigned int* __restrict__ bar,      // 8 counters, 128B apart, pre-zeroed
    int Tc)
{
    __shared__ __align__(16) float zbuf[8][32][132];   // 132 KB

    const int tid  = threadIdx.x;
    const int wave = tid >> 6;
    const int lane = tid & 63;
    const int lrow = lane & 15;
    const int quad = lane >> 4;

    // XCD swizzle: fid%8 = XCD; each XCD owns 4 cgs (2 MB weights, L2-resident)
    const int fid = blockIdx.x;
    const int xcd = fid & 7;
    const int s   = fid >> 3;           // 0..31
    const int cgi = xcd * 4 + (s & 3);  // 0..31
    const int rg  = s >> 2;             // 0..7
    const int rbase = rg * 32;
    const int cbase = cgi * 128;

    // fixed epilogue ownership -> c in registers
    const int b_loc = tid >> 4;          // 0..31
    const int cq    = tid & 15;
    const int oc    = cq * 8;            // 0..120
    const int bown  = rbase + b_loc;
    const int j0    = cgi * 32 + cq * 2;
    float c0 = 0.f, c1 = 0.f;

    unsigned int* const mybar = bar + rg * 32;
    unsigned int barTarget = 0;

    int t0 = 0, cur = 0;
    int tcc = (Tc < T_) ? Tc : T_;

    // ---- prologue: produce chunk 0's xz entirely (into xzA) ----
    {
        Prod P; P.t = wave; P.u = 0; prod_zero(P);
        while (P.t < tcc)
            prod_unit(P, tcc, 0, x, WXhi, WXlo, biasP, xzA,
                      rbase, cbase, lrow, quad);
    }
    __syncthreads();

    while (true) {
        const int nt0 = t0 + tcc;
        const int tcn = (nt0 < T_) ? ((T_ - nt0 < Tc) ? T_ - nt0 : Tc) : 0;
        float* const xzc = cur ? xzB : xzA;   // consume
        float* const xzn = cur ? xzA : xzB;   // produce (next chunk)

        Prod P; P.t = wave; P.u = 0; prod_zero(P);
        const int ntiles = (tcn > wave) ? ((tcn - wave + 7) >> 3) : 0;
        const int units  = ntiles * 16;
        const int Q      = (units + tcc - 1) / tcc;

        for (int tr = 0; tr < tcc; ++tr) {
            const int t = t0 + tr;
            const unsigned short* ih = (t & 1) ? h1hi : h0hi;
            const unsigned short* il = (t & 1) ? h1lo : h0lo;
            unsigned short* oh = (t & 1) ? h0hi : h1hi;
            unsigned short* ol = (t & 1) ? h0lo : h1lo;

            f32x4 acc[2][8];
            #pragma unroll
            for (int rs = 0; rs < 2; ++rs)
                #pragma unroll
                for (int cs = 0; cs < 8; ++cs)
                    acc[rs][cs] = (f32x4){0.f, 0.f, 0.f, 0.f};

            const int kb = wave * 128;
            #pragma unroll 1
            for (int kc4 = 0; kc4 < 4; ++kc4) {
                const int k = kb + kc4 * 32 + quad * 8;
                bf16x8 Ahi[2], Alo[2], Bh[8], Bl[8];
                // first half of W before the h-wait (L2 latency hides under it)
                #pragma unroll
                for (int cs = 0; cs < 4; ++cs) {
                    int off = (cbase + cs * 16 + lrow) * H_ + k;
                    Bh[cs] = *(const bf16x8*)(Whhi + off);
                    Bl[cs] = *(const bf16x8*)(Whlo + off);
                }
                {
                    int o0 = (rbase + 0 * 16 + lrow) * H_ + k;
                    int o1 = (rbase + 1 * 16 + lrow) * H_ + k;
                    load_h4(ih + o0, ih + o1, il + o0, il + o1,
                            Ahi[0], Ahi[1], Alo[0], Alo[1]);
                }
                #pragma unroll
                for (int cs = 4; cs < 8; ++cs) {
                    int off = (cbase + cs * 16 + lrow) * H_ + k;
                    Bh[cs] = *(const bf16x8*)(Whhi + off);
                    Bl[cs] = *(const bf16x8*)(Whlo + off);
                }
                #pragma unroll
                for (int rs = 0; rs < 2; ++rs)
                    #pragma unroll
                    for (int cs = 0; cs < 8; ++cs) {
                        acc[rs][cs] = __builtin_amdgcn_mfma_f32_16x16x32_bf16(Ahi[rs], Bh[cs], acc[rs][cs], 0, 0, 0);
                        acc[rs][cs] = __builtin_amdgcn_mfma_f32_16x16x32_bf16(Ahi[rs], Bl[cs], acc[rs][cs], 0, 0, 0);
                        acc[rs][cs] = __builtin_amdgcn_mfma_f32_16x16x32_bf16(Alo[rs], Bh[cs], acc[rs][cs], 0, 0, 0);
                    }
            }

            // per-wave partials to LDS
            #pragma unroll
            for (int rs = 0; rs < 2; ++rs)
                #pragma unroll
                for (int cs = 0; cs < 8; ++cs)
                    #pragma unroll
                    for (int r = 0; r < 4; ++r)
                        zbuf[wave][rs * 16 + quad * 4 + r][cs * 16 + lrow] = acc[rs][cs][r];
            __syncthreads();

            // reduce 8 partials + cell update (2 cells/thread)
            float zz[8];
            #pragma unroll
            for (int i = 0; i < 8; i += 4) {
                float s0 = 0.f, s1 = 0.f, s2 = 0.f, s3 = 0.f;
                #pragma unroll
                for (int w = 0; w < 8; ++w) {
                    float4 v = *(const float4*)&zbuf[w][b_loc][oc + i];
                    s0 += v.x; s1 += v.y; s2 += v.z; s3 += v.w;
                }
                zz[i] = s0; zz[i + 1] = s1; zz[i + 2] = s2; zz[i + 3] = s3;
            }

            const size_t xzoff = ((size_t)tr * B_ + bown) * N4H + cbase + oc;
            float4 xa = *(const float4*)(xzc + xzoff);
            float4 xb = *(const float4*)(xzc + xzoff + 4);
            zz[0] += xa.x; zz[1] += xa.y; zz[2] += xa.z; zz[3] += xa.w;
            zz[4] += xb.x; zz[5] += xb.y; zz[6] += xb.z; zz[7] += xb.w;

            float cold[2] = {c0, c1};
            unsigned short hh[2], hl[2];
            float cnew[2];
            #pragma unroll
            for (int j = 0; j < 2; ++j) {
                float zg = zz[4 * j + 0];
                float zi = zz[4 * j + 1];
                float zf = zz[4 * j + 2];
                float zo = zz[4 * j + 3];
                float g  = tanhf(zg);
                float ig = 1.f / (1.f + expf(-zi));
                float fg = 1.f / (1.f + expf(-zf));
                float og = 1.f / (1.f + expf(-zo));
                float cn = g * ig + cold[j] * fg;
                float hn = tanhf(cn) * og;
                cnew[j] = cn;
                unsigned short h16 = f2bf(hn);
                hh[j] = h16;
                hl[j] = f2bf(hn - bf2f(h16));
            }
            c0 = cnew[0]; c1 = cnew[1];
            store_h4(&oh[bown * H_ + j0], (unsigned)hh[0] | ((unsigned)hh[1] << 16));
            store_h4(&ol[bown * H_ + j0], (unsigned)hl[0] | ((unsigned)hl[1] << 16));

            // drain the inline-asm h stores (compiler's waitcnt tracking does
            // not see them), THEN block-barrier, THEN signal the cluster.
            drain_vmem();
            __syncthreads();

            if (t != T_ - 1) {
                barTarget += 32;
                if (tid == 0)
                    __hip_atomic_fetch_add(mybar, 1u, __ATOMIC_RELAXED,
                                           __HIP_MEMORY_SCOPE_AGENT);
                // fill the barrier bubble with next-chunk xz production
                for (int q = 0; q < Q; ++q)
                    prod_unit(P, tcn, nt0, x, WXhi, WXlo, biasP, xzn,
                              rbase, cbase, lrow, quad);
                if (tid == 0) {
                    while (__hip_atomic_load(mybar, __ATOMIC_RELAXED,
                                             __HIP_MEMORY_SCOPE_AGENT) < barTarget)
                        __builtin_amdgcn_s_sleep(1);
                }
                __syncthreads();
            }
        }

        if (tcn == 0) break;
        t0 = nt0; tcc = tcn; cur ^= 1;
    }
}

// ---------------------------------------------------------------------------
// Final projection + softmax: one block per batch row, 128 threads.
// ---------------------------------------------------------------------------
__global__ __launch_bounds__(128) void final_proj(
    const unsigned short* __restrict__ hhi, const unsigned short* __restrict__ hlo,
    const float* __restrict__ Why, const float* __restrict__ bhy,
    float* __restrict__ out)
{
    __shared__ float hsh[H_];
    __shared__ float red[O_];
    const int b = blockIdx.x, tid = threadIdx.x;

    for (int k = tid; k < H_; k += O_)
        hsh[k] = bf2f(hhi[(size_t)b * H_ + k]) + bf2f(hlo[(size_t)b * H_ + k]);
    __syncthreads();

    float s = bhy[tid];
    const float* w = Why + (size_t)tid * H_;
    #pragma unroll 4
    for (int k = 0; k < H_; k += 4) {
        float4 wv = *(const float4*)(w + k);
        s += hsh[k] * wv.x + hsh[k + 1] * wv.y + hsh[k + 2] * wv.z + hsh[k + 3] * wv.w;
    }

    red[tid] = s; __syncthreads();
    for (int off = 64; off > 0; off >>= 1) {
        if (tid < off) red[tid] = fmaxf(red[tid], red[tid + off]);
        __syncthreads();
    }
    float mx = red[0]; __syncthreads();
    float e = expf(s - mx);
    red[tid] = e; __syncthreads();
    for (int off = 64; off > 0; off >>= 1) {
        if (tid < off) red[tid] += red[tid + off];
        __syncthreads();
    }
    out[(size_t)b * O_ + tid] = e / red[0];
}

// ---------------------------------------------------------------------------
extern "C" void kernel_launch(void* const* d_in, const int* in_sizes, int n_in,
                              void* d_out, int out_size, void* d_ws, size_t ws_size,
                              hipStream_t stream)
{
    const float* x   = (const float*)d_in[0];
    const float* Wgx = (const float*)d_in[1];
    const float* bgx = (const float*)d_in[2];
    const float* Wgh = (const float*)d_in[3];
    const float* Wix = (const float*)d_in[4];
    const float* bix = (const float*)d_in[5];
    const float* Wih = (const float*)d_in[6];
    const float* Wfx = (const float*)d_in[7];
    const float* bfx = (const float*)d_in[8];
    const float* Wfh = (const float*)d_in[9];
    const float* Wox = (const float*)d_in[10];
    const float* box = (const float*)d_in[11];
    const float* Woh = (const float*)d_in[12];
    const float* Why = (const float*)d_in[13];
    const float* bhy = (const float*)d_in[14];

    // workspace layout (fixed ~22 MB + 2 x xz chunk buffers)
    unsigned short* Whhi = (unsigned short*)d_ws;                 // 4096*1024
    unsigned short* Whlo = Whhi + (size_t)N4H * H_;
    unsigned short* WXhi = Whlo + (size_t)N4H * H_;               // 4096*256
    unsigned short* WXlo = WXhi + (size_t)N4H * D_;
    float*          bP   = (float*)(WXlo + (size_t)N4H * D_);
    unsigned int*   bars = (unsigned int*)(bP + N4H);             // 1024 uints
    unsigned short* hA_hi = (unsigned short*)(bars + 1024);
    unsigned short* hA_lo = hA_hi + (size_t)B_ * H_;
    unsigned short* hB_hi = hA_lo + (size_t)B_ * H_;
    unsigned short* hB_lo = hB_hi + (size_t)B_ * H_;
    float*          xzBase = (float*)(hB_lo + (size_t)B_ * H_);

    const size_t fixed_bytes = (size_t)((char*)xzBase - (char*)d_ws);
    const size_t per_t = (size_t)B_ * N4H * sizeof(float);        // 4 MB per step
    int Tc = 1;
    if (ws_size > fixed_bytes) {
        size_t fit = (ws_size - fixed_bytes) / (2 * per_t);
        Tc = (fit > 32) ? 32 : (fit < 1 ? 1 : (int)fit);
    }
    float* xzA = xzBase;
    float* xzB = xzBase + (size_t)Tc * B_ * N4H;

    // zero barrier counters + h ping buffer (bars, hA_hi, hA_lo contiguous)
    hipMemsetAsync(bars, 0, 4096 + (size_t)B_ * H_ * 4, stream);

    const int totalW = N4H * (H_ + D_);
    pack_weights<<<(totalW + 255) / 256, 256, 0, stream>>>(
        Wgx, bgx, Wgh, Wix, bix, Wih, Wfx, bfx, Wfh, Wox, box, Woh,
        Whhi, Whlo, WXhi, WXlo, bP);

    void* kargs[] = {
        (void*)&x, (void*)&Whhi, (void*)&Whlo, (void*)&WXhi, (void*)&WXlo,
        (void*)&bP, (void*)&hA_hi, (void*)&hA_lo, (void*)&hB_hi, (void*)&hB_lo,
        (void*)&xzA, (void*)&xzB, (void*)&bars, (void*)&Tc
    };
    hipLaunchCooperativeKernel((const void*)lstm_persistent,
                               dim3(256), dim3(512), kargs, 0, stream);

    // T=512 even: last step (t=511, odd) wrote the A buffers
    final_proj<<<B_, 128, 0, stream>>>(hA_hi, hA_lo, Why, bhy, (float*)d_out);
}

// Round 7
// 13336.220 us; speedup vs baseline: 1.0205x; 1.0205x over previous
//
#include <hip/hip_runtime.h>
#include <math.h>

#define B_  256
#define T_  512
#define D_  256
#define H_  1024
#define O_  128
#define N4H 4096          // 4*H

typedef __attribute__((ext_vector_type(8))) short bf16x8;
typedef __attribute__((ext_vector_type(4))) float f32x4;

__device__ __forceinline__ unsigned short f2bf(float x) {
    union { float f; unsigned u; } v; v.f = x;
    unsigned r = v.u + 0x7fffu + ((v.u >> 16) & 1u);
    return (unsigned short)(r >> 16);
}
__device__ __forceinline__ float bf2f(unsigned short b) {
    union { float f; unsigned u; } v; v.u = ((unsigned)b) << 16;
    return v.f;
}
// cheap split: hi = truncated top-16, lo = rne(w - hi).
__device__ __forceinline__ void splitf(float w, short& hi, short& lo) {
    union { float f; unsigned u; } v; v.f = w;
    union { float f; unsigned u; } hf; hf.u = v.u & 0xffff0000u;
    hi = (short)(unsigned short)(v.u >> 16);
    lo = (short)f2bf(w - hf.f);
}

// 8 coherent 16B loads (sc0 sc1: bypass L1/L2, L3-coherent), NO waitcnt.
// "memory" clobber keeps any memory op (incl. the dependent LDS writes)
// from being scheduled before/into this block.
__device__ __forceinline__ void ld8_nowait(
    const unsigned short* p,
    bf16x8& r0, bf16x8& r1, bf16x8& r2, bf16x8& r3,
    bf16x8& r4, bf16x8& r5, bf16x8& r6, bf16x8& r7)
{
    asm volatile(
        "global_load_dwordx4 %0, %8, off sc0 sc1\n\t"
        "global_load_dwordx4 %1, %8, off offset:256 sc0 sc1\n\t"
        "global_load_dwordx4 %2, %8, off offset:512 sc0 sc1\n\t"
        "global_load_dwordx4 %3, %8, off offset:768 sc0 sc1\n\t"
        "global_load_dwordx4 %4, %8, off offset:1024 sc0 sc1\n\t"
        "global_load_dwordx4 %5, %8, off offset:1280 sc0 sc1\n\t"
        "global_load_dwordx4 %6, %8, off offset:1536 sc0 sc1\n\t"
        "global_load_dwordx4 %7, %8, off offset:1792 sc0 sc1"
        : "=&v"(r0), "=&v"(r1), "=&v"(r2), "=&v"(r3),
          "=&v"(r4), "=&v"(r5), "=&v"(r6), "=&v"(r7)
        : "v"(p)
        : "memory");
}
// Same, but ends with vmcnt(0): waits for ALL outstanding vmem, i.e. also
// the preceding ld8_nowait batch. One effective wait per staging.
__device__ __forceinline__ void ld8_wait(
    const unsigned short* p,
    bf16x8& r0, bf16x8& r1, bf16x8& r2, bf16x8& r3,
    bf16x8& r4, bf16x8& r5, bf16x8& r6, bf16x8& r7)
{
    asm volatile(
        "global_load_dwordx4 %0, %8, off sc0 sc1\n\t"
        "global_load_dwordx4 %1, %8, off offset:256 sc0 sc1\n\t"
        "global_load_dwordx4 %2, %8, off offset:512 sc0 sc1\n\t"
        "global_load_dwordx4 %3, %8, off offset:768 sc0 sc1\n\t"
        "global_load_dwordx4 %4, %8, off offset:1024 sc0 sc1\n\t"
        "global_load_dwordx4 %5, %8, off offset:1280 sc0 sc1\n\t"
        "global_load_dwordx4 %6, %8, off offset:1536 sc0 sc1\n\t"
        "global_load_dwordx4 %7, %8, off offset:1792 sc0 sc1\n\t"
        "s_waitcnt vmcnt(0)"
        : "=&v"(r0), "=&v"(r1), "=&v"(r2), "=&v"(r3),
          "=&v"(r4), "=&v"(r5), "=&v"(r6), "=&v"(r7)
        : "v"(p)
        : "memory");
}

// Coherent 4B store (write to coherence point, no dirty L2 lines).
__device__ __forceinline__ void store_h4(unsigned short* p, unsigned int d) {
    asm volatile("global_store_dword %0, %1, off sc0 sc1"
                 :: "v"(p), "v"(d) : "memory");
}
// Coherent 4B load (flag poll).
__device__ __forceinline__ unsigned ld_flag(const unsigned* p) {
    unsigned v;
    asm volatile("global_load_dword %0, %1, off sc0 sc1\n\ts_waitcnt vmcnt(0)"
                 : "=v"(v) : "v"(p) : "memory");
    return v;
}
__device__ __forceinline__ void st_flag(unsigned* p, unsigned v) {
    asm volatile("global_store_dword %0, %1, off sc0 sc1"
                 :: "v"(p), "v"(v) : "memory");
}
// Drain ALL vmem incl. inline-asm stores the compiler does not track.
__device__ __forceinline__ void drain_vmem() {
    asm volatile("s_waitcnt vmcnt(0)" ::: "memory");
}

// LDS h layout: [k8][row] 16B tiles, XOR-swizzled. Index in ushorts (all
// results multiples of 8 ushorts = 16B -> aligned b128 access).
#define HIDX(k8, row) (((((k8) * 32) + (row)) * 8) ^ (((k8) & 7) * 8))

// ---------------------------------------------------------------------------
// Pack weights, gate-interleaved rows n' = 4*j + gate (0=g,1=i,2=f,3=o).
// ---------------------------------------------------------------------------
__global__ __launch_bounds__(256) void pack_weights(
    const float* __restrict__ Wgx, const float* __restrict__ bgx, const float* __restrict__ Wgh,
    const float* __restrict__ Wix, const float* __restrict__ bix, const float* __restrict__ Wih,
    const float* __restrict__ Wfx, const float* __restrict__ bfx, const float* __restrict__ Wfh,
    const float* __restrict__ Wox, const float* __restrict__ box, const float* __restrict__ Woh,
    unsigned short* __restrict__ Whhi, unsigned short* __restrict__ Whlo,
    unsigned short* __restrict__ WXhi, unsigned short* __restrict__ WXlo,
    float* __restrict__ biasP)
{
    int idx = blockIdx.x * 256 + threadIdx.x;
    const int K = H_ + D_;
    const int total = N4H * K;
    if (idx < total) {
        int np = idx / K;
        int k  = idx - np * K;
        int j = np >> 2, g = np & 3;
        const float* Wh = (g == 0) ? Wgh : (g == 1) ? Wih : (g == 2) ? Wfh : Woh;
        const float* Wx = (g == 0) ? Wgx : (g == 1) ? Wix : (g == 2) ? Wfx : Wox;
        float w = (k < H_) ? Wh[j * H_ + k] : Wx[j * D_ + (k - H_)];
        unsigned short hi = f2bf(w);
        unsigned short lo = f2bf(w - bf2f(hi));
        if (k < H_) { Whhi[np * H_ + k] = hi; Whlo[np * H_ + k] = lo; }
        else        { WXhi[np * D_ + (k - H_)] = hi; WXlo[np * D_ + (k - H_)] = lo; }
    }
    if (idx < N4H) {
        int j = idx >> 2, g = idx & 3;
        const float* bx = (g == 0) ? bgx : (g == 1) ? bix : (g == 2) ? bfx : box;
        biasP[idx] = bx[j];
    }
}

// ---------------------------------------------------------------------------
// Persistent kernel. 256 blocks x 512 threads (8 waves), 1 block/CU.
// Partition: 8 clusters (rg, 32 batch rows each) x 32 col-blocks (128 packed
// cols each). Per step:
//   - cooperative stage of the cluster h slice (32x1024 hi+lo = 128 KB) into
//     LDS with ONE effective vmcnt per thread (bulk, BW-bound);
//   - each wave: GEMM 32 rows x 16 cols x K=1024 (A from LDS, W from L2),
//     wave-local transpose scratch, cell update, sc0/sc1 h store;
//   - flag barrier per cluster (one store + 32 parallel flag polls).
// Weights stay plain->L2-resident (2 MB/XCD). c state in 2 VGPRs/thread.
// xz produced per chunk (phase A, block-local, bursty -> x L2-friendly).
// ---------------------------------------------------------------------------
__global__ __launch_bounds__(512, 2) void lstm_persistent(
    const float* __restrict__ x,
    const unsigned short* __restrict__ Whhi, const unsigned short* __restrict__ Whlo,
    const unsigned short* __restrict__ WXhi, const unsigned short* __restrict__ WXlo,
    const float* __restrict__ biasP,
    unsigned short* __restrict__ h0hi, unsigned short* __restrict__ h0lo,
    unsigned short* __restrict__ h1hi, unsigned short* __restrict__ h1lo,
    float* __restrict__ xz,
    unsigned int* __restrict__ flg,      // 8*32 flags, pre-zeroed
    int Tc)
{
    __shared__ __align__(16) unsigned short hsHI[32768];   // 64 KB [k8][row] swz
    __shared__ __align__(16) unsigned short hsLO[32768];   // 64 KB
    __shared__ __align__(16) float zsc[8][32][20];         // 20 KB (80B rows: 16B-aligned float4)

    const int tid  = threadIdx.x;
    const int wave = tid >> 6;
    const int lane = tid & 63;
    const int lrow = lane & 15;
    const int quad = lane >> 4;

    // XCD swizzle: fid%8 = XCD; each XCD owns 4 cgs (2 MB weights, L2-resident)
    const int fid = blockIdx.x;
    const int xcd = fid & 7;
    const int s   = fid >> 3;           // 0..31
    const int cgi = xcd * 4 + (s & 3);  // 0..31
    const int rg  = s >> 2;             // 0..7
    const int rbase = rg * 32;
    const int cbase = cgi * 128;

    // stage assignment: 4 consecutive threads = 4 consecutive k-slots (64B
    // coalesced global), rows vary next.
    const int srow = (tid >> 2) & 31;
    const int sks  = (tid & 3) | (((tid >> 7) & 3) << 2);   // 0..15

    // epilogue ownership (fixed all run -> c in registers)
    const int erow = lane >> 1;          // 0..31
    const int eps  = lane & 1;           // col-half within wave's 16 cols
    const int bown = rbase + erow;
    const int j0   = cgi * 32 + wave * 4 + eps * 2;   // first of 2 cells
    float c0 = 0.f, c1 = 0.f;

    unsigned int* const myflag = flg + rg * 32 + cgi;
    const unsigned int* const pollbase = flg + rg * 32;

    for (int t0 = 0; t0 < T_; t0 += Tc) {
        const int tc = (T_ - t0 < Tc) ? (T_ - t0) : Tc;

        // ================= phase A: xz for this chunk (block-local) ========
        for (int tr = wave; tr < tc; tr += 8) {
            const int t = t0 + tr;
            #pragma unroll 1
            for (int hf = 0; hf < 2; ++hf) {
                f32x4 xacc[2][4];
                #pragma unroll
                for (int rs = 0; rs < 2; ++rs)
                    #pragma unroll
                    for (int cs = 0; cs < 4; ++cs)
                        xacc[rs][cs] = (f32x4){0.f, 0.f, 0.f, 0.f};
                #pragma unroll 1
                for (int kc = 0; kc < 8; ++kc) {
                    const int kx = kc * 32 + quad * 8;
                    bf16x8 Ahi[2], Alo[2];
                    #pragma unroll
                    for (int rs = 0; rs < 2; ++rs) {
                        const float* p = x + (size_t)(rbase + rs * 16 + lrow) * (T_ * D_)
                                           + (size_t)t * D_ + kx;
                        float4 v0 = *(const float4*)p;
                        float4 v1 = *(const float4*)(p + 4);
                        float vv[8] = {v0.x, v0.y, v0.z, v0.w, v1.x, v1.y, v1.z, v1.w};
                        #pragma unroll
                        for (int j = 0; j < 8; ++j) {
                            short hi, lo; splitf(vv[j], hi, lo);
                            Ahi[rs][j] = hi; Alo[rs][j] = lo;
                        }
                    }
                    bf16x8 Bh[4], Bl[4];
                    #pragma unroll
                    for (int cs = 0; cs < 4; ++cs) {
                        size_t off = (size_t)(cbase + hf * 64 + cs * 16 + lrow) * D_ + kx;
                        Bh[cs] = *(const bf16x8*)(WXhi + off);
                        Bl[cs] = *(const bf16x8*)(WXlo + off);
                    }
                    #pragma unroll
                    for (int rs = 0; rs < 2; ++rs)
                        #pragma unroll
                        for (int cs = 0; cs < 4; ++cs) {
                            xacc[rs][cs] = __builtin_amdgcn_mfma_f32_16x16x32_bf16(Ahi[rs], Bh[cs], xacc[rs][cs], 0, 0, 0);
                            xacc[rs][cs] = __builtin_amdgcn_mfma_f32_16x16x32_bf16(Ahi[rs], Bl[cs], xacc[rs][cs], 0, 0, 0);
                            xacc[rs][cs] = __builtin_amdgcn_mfma_f32_16x16x32_bf16(Alo[rs], Bh[cs], xacc[rs][cs], 0, 0, 0);
                        }
                }
                #pragma unroll
                for (int cs = 0; cs < 4; ++cs) {
                    int col = cbase + hf * 64 + cs * 16 + lrow;
                    float bv = biasP[col];
                    #pragma unroll
                    for (int rs = 0; rs < 2; ++rs) {
                        int row0 = rbase + rs * 16 + quad * 4;
                        #pragma unroll
                        for (int r = 0; r < 4; ++r)
                            xz[(size_t)(tr * B_ + row0 + r) * N4H + col] = xacc[rs][cs][r] + bv;
                    }
                }
            }
        }
        __syncthreads();   // xz visible block-wide before steps consume it

        // ================= recurrent steps =================================
        for (int tr = 0; tr < tc; ++tr) {
            const int t = t0 + tr;
            const unsigned short* ih = (t & 1) ? h1hi : h0hi;
            const unsigned short* il = (t & 1) ? h1lo : h0lo;
            unsigned short* oh = (t & 1) ? h0hi : h1hi;
            unsigned short* ol = (t & 1) ? h0lo : h1lo;

            // ---- stage cluster h slice into LDS (one effective vmcnt) -----
            {
                const unsigned short* phi = ih + (size_t)(rbase + srow) * H_ + sks * 8;
                const unsigned short* plo = il + (size_t)(rbase + srow) * H_ + sks * 8;
                bf16x8 H0, H1, H2, H3, H4, H5, H6, H7;
                bf16x8 L0, L1, L2, L3, L4, L5, L6, L7;
                ld8_nowait(phi, H0, H1, H2, H3, H4, H5, H6, H7);
                ld8_wait  (plo, L0, L1, L2, L3, L4, L5, L6, L7);
                *(bf16x8*)&hsHI[HIDX(sks +   0, srow)] = H0;
                *(bf16x8*)&hsHI[HIDX(sks +  16, srow)] = H1;
                *(bf16x8*)&hsHI[HIDX(sks +  32, srow)] = H2;
                *(bf16x8*)&hsHI[HIDX(sks +  48, srow)] = H3;
                *(bf16x8*)&hsHI[HIDX(sks +  64, srow)] = H4;
                *(bf16x8*)&hsHI[HIDX(sks +  80, srow)] = H5;
                *(bf16x8*)&hsHI[HIDX(sks +  96, srow)] = H6;
                *(bf16x8*)&hsHI[HIDX(sks + 112, srow)] = H7;
                *(bf16x8*)&hsLO[HIDX(sks +   0, srow)] = L0;
                *(bf16x8*)&hsLO[HIDX(sks +  16, srow)] = L1;
                *(bf16x8*)&hsLO[HIDX(sks +  32, srow)] = L2;
                *(bf16x8*)&hsLO[HIDX(sks +  48, srow)] = L3;
                *(bf16x8*)&hsLO[HIDX(sks +  64, srow)] = L4;
                *(bf16x8*)&hsLO[HIDX(sks +  80, srow)] = L5;
                *(bf16x8*)&hsLO[HIDX(sks +  96, srow)] = L6;
                *(bf16x8*)&hsLO[HIDX(sks + 112, srow)] = L7;
            }
            __syncthreads();

            // ---- per-wave GEMM: 32 rows x 16 cols, K=1024 -----------------
            f32x4 aH0 = (f32x4){0.f,0.f,0.f,0.f}, aL0 = aH0, aX0 = aH0;
            f32x4 aH1 = aH0, aL1 = aH0, aX1 = aH0;
            {
                const unsigned short* wbh = Whhi + (size_t)(cbase + wave * 16 + lrow) * H_ + quad * 8;
                const unsigned short* wbl = Whlo + (size_t)(cbase + wave * 16 + lrow) * H_ + quad * 8;
                #pragma unroll 4
                for (int kc = 0; kc < 32; ++kc) {
                    const int k8 = kc * 4 + quad;
                    bf16x8 Bh = *(const bf16x8*)(wbh + kc * 32);
                    bf16x8 Bl = *(const bf16x8*)(wbl + kc * 32);
                    bf16x8 Ah0 = *(const bf16x8*)&hsHI[HIDX(k8, lrow)];
                    bf16x8 Ah1 = *(const bf16x8*)&hsHI[HIDX(k8, 16 + lrow)];
                    bf16x8 Al0 = *(const bf16x8*)&hsLO[HIDX(k8, lrow)];
                    bf16x8 Al1 = *(const bf16x8*)&hsLO[HIDX(k8, 16 + lrow)];
                    aH0 = __builtin_amdgcn_mfma_f32_16x16x32_bf16(Ah0, Bh, aH0, 0, 0, 0);
                    aL0 = __builtin_amdgcn_mfma_f32_16x16x32_bf16(Ah0, Bl, aL0, 0, 0, 0);
                    aX0 = __builtin_amdgcn_mfma_f32_16x16x32_bf16(Al0, Bh, aX0, 0, 0, 0);
                    aH1 = __builtin_amdgcn_mfma_f32_16x16x32_bf16(Ah1, Bh, aH1, 0, 0, 0);
                    aL1 = __builtin_amdgcn_mfma_f32_16x16x32_bf16(Ah1, Bl, aL1, 0, 0, 0);
                    aX1 = __builtin_amdgcn_mfma_f32_16x16x32_bf16(Al1, Bh, aX1, 0, 0, 0);
                }
            }
            f32x4 a0 = aH0 + aL0 + aX0;
            f32x4 a1 = aH1 + aL1 + aX1;

            // ---- wave-local transpose via zsc (20-float rows: aligned) ----
            #pragma unroll
            for (int r = 0; r < 4; ++r) {
                zsc[wave][quad * 4 + r][lrow] = a0[r];
                zsc[wave][16 + quad * 4 + r][lrow] = a1[r];
            }
            // each lane: row = lane>>1, cols eps*8..+8 of wave's 16
            float zz[8];
            {
                float4 v0 = *(const float4*)&zsc[wave][erow][eps * 8];
                float4 v1 = *(const float4*)&zsc[wave][erow][eps * 8 + 4];
                zz[0] = v0.x; zz[1] = v0.y; zz[2] = v0.z; zz[3] = v0.w;
                zz[4] = v1.x; zz[5] = v1.y; zz[6] = v1.z; zz[7] = v1.w;
            }
            const size_t xzoff = ((size_t)tr * B_ + bown) * N4H + cbase + wave * 16 + eps * 8;
            float4 xa = *(const float4*)(xz + xzoff);
            float4 xb = *(const float4*)(xz + xzoff + 4);
            zz[0] += xa.x; zz[1] += xa.y; zz[2] += xa.z; zz[3] += xa.w;
            zz[4] += xb.x; zz[5] += xb.y; zz[6] += xb.z; zz[7] += xb.w;

            float cold[2] = {c0, c1};
            float cnew[2];
            unsigned short hh[2], hl[2];
            #pragma unroll
            for (int j = 0; j < 2; ++j) {
                float zg = zz[4 * j + 0];
                float zi = zz[4 * j + 1];
                float zf = zz[4 * j + 2];
                float zo = zz[4 * j + 3];
                float g  = tanhf(zg);
                float ig = 1.f / (1.f + expf(-zi));
                float fg = 1.f / (1.f + expf(-zf));
                float og = 1.f / (1.f + expf(-zo));
                float cn = g * ig + cold[j] * fg;
                float hn = tanhf(cn) * og;
                cnew[j] = cn;
                unsigned short h16 = f2bf(hn);
                hh[j] = h16;
                hl[j] = f2bf(hn - bf2f(h16));
            }
            c0 = cnew[0]; c1 = cnew[1];
            store_h4(&oh[(size_t)bown * H_ + j0], (unsigned)hh[0] | ((unsigned)hh[1] << 16));
            store_h4(&ol[(size_t)bown * H_ + j0], (unsigned)hl[0] | ((unsigned)hl[1] << 16));

            // drain untracked asm stores, then block barrier, then cluster flag
            drain_vmem();
            __syncthreads();

            if (t != T_ - 1) {
                const unsigned want = (unsigned)(t + 1);
                if (tid == 0) st_flag(myflag, want);
                if (wave == 0) {
                    const unsigned* fp = pollbase + (lane & 31);
                    while (ld_flag(fp) < want) __builtin_amdgcn_s_sleep(2);
                }
                __syncthreads();
            }
        }
    }
}

// ---------------------------------------------------------------------------
// Final projection + softmax: one block per batch row, 128 threads.
// ---------------------------------------------------------------------------
__global__ __launch_bounds__(128) void final_proj(
    const unsigned short* __restrict__ hhi, const unsigned short* __restrict__ hlo,
    const float* __restrict__ Why, const float* __restrict__ bhy,
    float* __restrict__ out)
{
    __shared__ float hsh[H_];
    __shared__ float red[O_];
    const int b = blockIdx.x, tid = threadIdx.x;

    for (int k = tid; k < H_; k += O_)
        hsh[k] = bf2f(hhi[(size_t)b * H_ + k]) + bf2f(hlo[(size_t)b * H_ + k]);
    __syncthreads();

    float s = bhy[tid];
    const float* w = Why + (size_t)tid * H_;
    #pragma unroll 4
    for (int k = 0; k < H_; k += 4) {
        float4 wv = *(const float4*)(w + k);
        s += hsh[k] * wv.x + hsh[k + 1] * wv.y + hsh[k + 2] * wv.z + hsh[k + 3] * wv.w;
    }

    red[tid] = s; __syncthreads();
    for (int off = 64; off > 0; off >>= 1) {
        if (tid < off) red[tid] = fmaxf(red[tid], red[tid + off]);
        __syncthreads();
    }
    float mx = red[0]; __syncthreads();
    float e = expf(s - mx);
    red[tid] = e; __syncthreads();
    for (int off = 64; off > 0; off >>= 1) {
        if (tid < off) red[tid] += red[tid + off];
        __syncthreads();
    }
    out[(size_t)b * O_ + tid] = e / red[0];
}

// ---------------------------------------------------------------------------
extern "C" void kernel_launch(void* const* d_in, const int* in_sizes, int n_in,
                              void* d_out, int out_size, void* d_ws, size_t ws_size,
                              hipStream_t stream)
{
    const float* x   = (const float*)d_in[0];
    const float* Wgx = (const float*)d_in[1];
    const float* bgx = (const float*)d_in[2];
    const float* Wgh = (const float*)d_in[3];
    const float* Wix = (const float*)d_in[4];
    const float* bix = (const float*)d_in[5];
    const float* Wih = (const float*)d_in[6];
    const float* Wfx = (const float*)d_in[7];
    const float* bfx = (const float*)d_in[8];
    const float* Wfh = (const float*)d_in[9];
    const float* Wox = (const float*)d_in[10];
    const float* box = (const float*)d_in[11];
    const float* Woh = (const float*)d_in[12];
    const float* Why = (const float*)d_in[13];
    const float* bhy = (const float*)d_in[14];

    // workspace layout (fixed ~22 MB + xz chunk buffer)
    unsigned short* Whhi = (unsigned short*)d_ws;                 // 4096*1024
    unsigned short* Whlo = Whhi + (size_t)N4H * H_;
    unsigned short* WXhi = Whlo + (size_t)N4H * H_;               // 4096*256
    unsigned short* WXlo = WXhi + (size_t)N4H * D_;
    float*          bP   = (float*)(WXlo + (size_t)N4H * D_);
    unsigned int*   flgs = (unsigned int*)(bP + N4H);             // 1024 uints
    unsigned short* hA_hi = (unsigned short*)(flgs + 1024);
    unsigned short* hA_lo = hA_hi + (size_t)B_ * H_;
    unsigned short* hB_hi = hA_lo + (size_t)B_ * H_;
    unsigned short* hB_lo = hB_hi + (size_t)B_ * H_;
    float*          xz    = (float*)(hB_lo + (size_t)B_ * H_);

    const size_t fixed_bytes = (size_t)((char*)xz - (char*)d_ws);
    const size_t per_t = (size_t)B_ * N4H * sizeof(float);        // 4 MB per step
    int Tc = 1;
    if (ws_size > fixed_bytes) {
        size_t fit = (ws_size - fixed_bytes) / per_t;
        Tc = (fit > 32) ? 32 : (fit < 1 ? 1 : (int)fit);
    }

    // zero flags + h ping buffers (flgs, hA_hi, hA_lo contiguous)
    hipMemsetAsync(flgs, 0, 4096 + (size_t)B_ * H_ * 4, stream);

    const int totalW = N4H * (H_ + D_);
    pack_weights<<<(totalW + 255) / 256, 256, 0, stream>>>(
        Wgx, bgx, Wgh, Wix, bix, Wih, Wfx, bfx, Wfh, Wox, box, Woh,
        Whhi, Whlo, WXhi, WXlo, bP);

    void* kargs[] = {
        (void*)&x, (void*)&Whhi, (void*)&Whlo, (void*)&WXhi, (void*)&WXlo,
        (void*)&bP, (void*)&hA_hi, (void*)&hA_lo, (void*)&hB_hi, (void*)&hB_lo,
        (void*)&xz, (void*)&flgs, (void*)&Tc
    };
    hipLaunchCooperativeKernel((const void*)lstm_persistent,
                               dim3(256), dim3(512), kargs, 0, stream);

    // T=512 even: last step (t=511, odd) wrote the A buffers
    final_proj<<<B_, 128, 0, stream>>>(hA_hi, hA_lo, Why, bhy, (float*)d_out);
}